// Round 6
// baseline (1301.283 us; speedup 1.0000x reference)
//
#include <hip/hip_runtime.h>

typedef unsigned int u32;

#define NB 16
#define NPT 1024
#define NP 512
#define NS 32
#define DF 64
#define RAD2 0.04f
#define EPSQ 1e-5f
#define CNTF 786432.0f   // 48*512*32
#define NGRP 8192        // NB*NP
#define TCAP 96
#define TSLOT 128
#define NTILE_MAX 2731   // ceil(NGRP*NS / TCAP)

// --- np-matching (contraction-proof) arithmetic -------------------------
__device__ __forceinline__ float rmul(float a, float b){ return __fmul_rn(a,b); }
__device__ __forceinline__ float radd(float a, float b){ return __fadd_rn(a,b); }
__device__ __forceinline__ float sq3(float a, float b, float c){
  return radd(radd(rmul(a,a), rmul(b,b)), rmul(c,c));
}

__device__ __forceinline__ float wave_sum64(float v){
  #pragma unroll
  for(int m=1;m<64;m<<=1) v += __shfl_xor(v, m, 64);
  return v;
}

// DPP argmax combine carrying (dist m, index mi, coords mx,my,mz).
// Take candidate if strictly greater, or equal with smaller index.
#define DPPC5(CTRL) do{ \
  float _ov = __int_as_float(__builtin_amdgcn_mov_dpp(__float_as_int(m ), (CTRL), 0xF, 0xF, true)); \
  int   _oi =               __builtin_amdgcn_mov_dpp(mi,                  (CTRL), 0xF, 0xF, true);  \
  float _ox = __int_as_float(__builtin_amdgcn_mov_dpp(__float_as_int(mx), (CTRL), 0xF, 0xF, true)); \
  float _oy = __int_as_float(__builtin_amdgcn_mov_dpp(__float_as_int(my), (CTRL), 0xF, 0xF, true)); \
  float _oz = __int_as_float(__builtin_amdgcn_mov_dpp(__float_as_int(mz), (CTRL), 0xF, 0xF, true)); \
  bool _tk = (_ov > m) || (_ov == m && _oi < mi); \
  m  = _tk ? _ov : m;  mi = _tk ? _oi : mi; \
  mx = _tk ? _ox : mx; my = _tk ? _oy : my; mz = _tk ? _oz : mz; \
}while(0)

// Full-wave argmax over dist[16]/lane (global index n = lane*16 + j), ALSO
// returning the winner's coordinates (no memory access). Adjacent pairing at
// every tree level => tie -> lower index exactly (argmax first-index rule).
__device__ __forceinline__ void wave_argmax_xyz(const float* dist,
                                                const float* px, const float* py, const float* pz,
                                                int lane,
                                                float& qx, float& qy, float& qz){
  float v8[8]; int j8[8]; float x8[8], y8[8], z8[8];
  #pragma unroll
  for(int q=0;q<8;q++){
    bool tk = dist[2*q+1] > dist[2*q];
    v8[q] = tk ? dist[2*q+1] : dist[2*q];
    j8[q] = tk ? 2*q+1 : 2*q;
    x8[q] = tk ? px[2*q+1] : px[2*q];
    y8[q] = tk ? py[2*q+1] : py[2*q];
    z8[q] = tk ? pz[2*q+1] : pz[2*q];
  }
  float v4[4]; int j4[4]; float x4[4], y4[4], z4[4];
  #pragma unroll
  for(int q=0;q<4;q++){
    bool tk = v8[2*q+1] > v8[2*q];
    v4[q] = tk ? v8[2*q+1] : v8[2*q];
    j4[q] = tk ? j8[2*q+1] : j8[2*q];
    x4[q] = tk ? x8[2*q+1] : x8[2*q];
    y4[q] = tk ? y8[2*q+1] : y8[2*q];
    z4[q] = tk ? z8[2*q+1] : z8[2*q];
  }
  float v2[2]; int j2[2]; float x2[2], y2[2], z2[2];
  #pragma unroll
  for(int q=0;q<2;q++){
    bool tk = v4[2*q+1] > v4[2*q];
    v2[q] = tk ? v4[2*q+1] : v4[2*q];
    j2[q] = tk ? j4[2*q+1] : j4[2*q];
    x2[q] = tk ? x4[2*q+1] : x4[2*q];
    y2[q] = tk ? y4[2*q+1] : y4[2*q];
    z2[q] = tk ? z4[2*q+1] : z4[2*q];
  }
  bool tk = v2[1] > v2[0];
  float m  = tk ? v2[1] : v2[0];
  int   mi = lane*16 + (tk ? j2[1] : j2[0]);
  float mx = tk ? x2[1] : x2[0];
  float my = tk ? y2[1] : y2[0];
  float mz = tk ? z2[1] : z2[0];
  DPPC5(0xB1);   // quad_perm xor1
  DPPC5(0x4E);   // quad_perm xor2
  DPPC5(0x124);  // row_ror:4
  DPPC5(0x128);  // row_ror:8   -> row-16 reduced
  DPPC5(0x142);  // row_bcast15
  DPPC5(0x143);  // row_bcast31 -> lane 63 holds full 64-lane argmax
  qx = __int_as_float(__builtin_amdgcn_readlane(__float_as_int(mx), 63));
  qy = __int_as_float(__builtin_amdgcn_readlane(__float_as_int(my), 63));
  qz = __int_as_float(__builtin_amdgcn_readlane(__float_as_int(mz), 63));
}

// ======================= FPS (single wave, zero-memory loop) + prep ========
template<int PT>
__global__ __launch_bounds__(256) void fps_combo(const float* __restrict__ xyz,
                                                 float* __restrict__ out0,
                                                 const float* __restrict__ pts,
                                                 float* __restrict__ ptsT,
                                                 u32* __restrict__ witem){
  const int bid = blockIdx.x;
  const int t = threadIdx.x;
  if(bid >= NB){
    const int gid = (bid - NB)*256 + t;
    if(gid < NTILE_MAX*TSLOT) witem[gid] = 0xFFFFFFFFu;
    if constexpr(PT){
      const int w = gid >> 6, ln = gid & 63;
      if(w < 48*16){
        const int b3 = w >> 4, n0 = (w & 15) << 6;
        const float* src = pts + (((size_t)b3*64 + ln) << 10);
        float* dst = ptsT + (((size_t)b3*1024 + n0) << 6) + ln;
        #pragma unroll 4
        for(int i=0;i<64;i++) dst[(size_t)i << 6] = src[n0 + i];
      }
    }
    return;
  }
  if(t >= 64) return;
  const int lane = t;
  const int b = bid;
  const float* xb = xyz + b*3*NPT;
  float px[16], py[16], pz[16], dist[16];
  #pragma unroll
  for(int j=0;j<16;j++){
    const int n = lane*16 + j;
    px[j] = xb[n]; py[j] = xb[NPT+n]; pz[j] = xb[2*NPT+n];
  }
  // centroid
  float sx=0.f, sy=0.f, sz=0.f;
  #pragma unroll
  for(int j=0;j<16;j++){ sx+=px[j]; sy+=py[j]; sz+=pz[j]; }
  sx = wave_sum64(sx); sy = wave_sum64(sy); sz = wave_sum64(sz);
  const float cx = sx/1024.f, cy = sy/1024.f, cz = sz/1024.f;
  #pragma unroll
  for(int j=0;j<16;j++){
    float dx = px[j]-cx, dy = py[j]-cy, dz = pz[j]-cz;
    dist[j] = fminf(1e10f, sq3(dx,dy,dz));
  }
  float qx, qy, qz;
  wave_argmax_xyz(dist, px, py, pz, lane, qx, qy, qz);
  for(int it=0; it<NP; ++it){
    if(lane == 0){
      out0[(b*3+0)*NP + it] = qx;
      out0[(b*3+1)*NP + it] = qy;
      out0[(b*3+2)*NP + it] = qz;
    }
    #pragma unroll
    for(int j=0;j<16;j++){
      float dx = px[j]-qx, dy = py[j]-qy, dz = pz[j]-qz;
      float nd = sq3(dx,dy,dz);
      dist[j] = fminf(dist[j], nd);
    }
    wave_argmax_xyz(dist, px, py, pz, lane, qx, qy, qz);
  }
}

// ======================= Ball query (+cnt) =======================
__global__ __launch_bounds__(256) void ball_kernel(const float* __restrict__ xyz,
                                                   const float* __restrict__ out0,
                                                   int* __restrict__ idxb,
                                                   int* __restrict__ cntb){
  const int gw = (blockIdx.x * 256 + threadIdx.x) >> 6;
  const int lane = threadIdx.x & 63;
  const int b = gw >> 9;
  const int s = gw & 511;
  const float s0 = out0[(b*3+0)*NP + s];
  const float s1 = out0[(b*3+1)*NP + s];
  const float s2 = out0[(b*3+2)*NP + s];
  const float ss = sq3(s0,s1,s2);
  const float* xb = xyz + b*3*NPT;
  int base = 0;
  int* row = idxb + (b*NP + s)*NS;
  for(int chk=0; chk<16 && base<NS; ++chk){
    const int n = chk*64 + lane;
    float d0 = xb[n], d1 = xb[NPT+n], d2 = xb[2*NPT+n];
    float dd = sq3(d0,d1,d2);
    float p  = radd(radd(rmul(s0,d0), rmul(s1,d1)), rmul(s2,d2));
    float sqr = radd(radd(rmul(-2.0f,p), ss), dd);
    bool inc = !(sqr > RAD2);
    unsigned long long mask = __ballot(inc);
    if(inc){
      int slot = base + __popcll(mask & ((1ull<<lane)-1ull));
      if(slot < NS) row[slot] = n;
    }
    base += __popcll(mask);
  }
  if(lane==0) cntb[gw] = (base < NS) ? base : NS;
}

// ======================= pack: 1024 threads, 8 groups each =======================
__global__ __launch_bounds__(1024) void pack_kernel(const int* __restrict__ cntb,
                                                    const int* __restrict__ idxb,
                                                    u32* __restrict__ witem,
                                                    int* __restrict__ ntile_dev){
  const int t = threadIdx.x;
  const int lane = t & 63;
  const int wv = t >> 6;
  int c[8]; int s0 = 0;
  #pragma unroll
  for(int i=0;i<8;i++){ c[i] = cntb[t*8+i]; s0 += c[i]; }
  int pre = s0;
  #pragma unroll
  for(int d=1; d<64; d<<=1){
    int v = __shfl_up(pre, d, 64);
    if(lane >= d) pre += v;
  }
  __shared__ int wsum[16];
  if(lane==63) wsum[wv] = pre;
  __syncthreads();
  int wo = 0;
  #pragma unroll
  for(int w=0;w<16;w++) if(w < wv) wo += wsum[w];
  int m = wo + pre - s0;
  if(t==1023) *ntile_dev = (wo + pre + TCAP - 1) / TCAP;
  #pragma unroll
  for(int i=0;i<8;i++){
    const int g = t*8+i; const int cc = c[i];
    const int tile = m / TCAP; const int slot = m - TCAP*tile;
    const int* row = idxb + g*NS;
    for(int j=0;j<cc;j++){
      witem[tile*TSLOT + slot + j] = (u32)((g<<15) | (j<<10) | row[j]);
    }
    m += cc;
  }
}

// ======================= Fused MLP chain over packed tiles =======================
template<int DEPTH, int PT>
__global__ __launch_bounds__(384) void pass_kernel(
  const float* __restrict__ xyz, const float* __restrict__ ptsrc,
  const float* __restrict__ W0, const float* __restrict__ W1, const float* __restrict__ W2,
  const float* __restrict__ out0, const u32* __restrict__ witem,
  const int* __restrict__ cntb, const int* __restrict__ ntile_dev,
  const float* __restrict__ inv1, const float* __restrict__ inv2,
  float* __restrict__ part, float* __restrict__ out1)
{
  const int t = threadIdx.x;
  const int c3 = t >> 7;
  const int r  = t & 127;
  const int lane = t & 63;
  const int wv = t >> 6;
  const int bi = blockIdx.x;

  if(bi >= *ntile_dev) return;   // fin reduces only active tiles

  __shared__ float sq[3][128][17];
  __shared__ float wstat[6][128];
  for(int i=t; i<6*128; i+=384) (&wstat[0][0])[i] = 0.f;
  __syncthreads();

  const u32 w = witem[bi*TSLOT + r];
  const bool valid = (w != 0xFFFFFFFFu);
  const int bs = valid ? (int)(w >> 15) : 0;
  const int j  = valid ? (int)((w >> 10) & 31) : 1;
  const int n  = valid ? (int)(w & 1023) : 0;
  const int b = bs >> 9;
  const int s = bs & 511;
  const int b3 = b*3 + c3;
  const int cv = cntb[bs];
  const float wgt = valid ? ((j==0) ? (float)(33 - cv) : 1.0f) : 0.0f;

  const float gx = xyz[b3*NPT + n];
  const float cx = out0[b3*NP + s];
  float x0[66];
  x0[0] = gx - cx;
  x0[1] = gx;
  if constexpr(PT){
    const float4* pr4 = reinterpret_cast<const float4*>(ptsrc + (((size_t)b3<<10) + (size_t)n)*DF);
    #pragma unroll
    for(int q=0;q<16;q++){
      float4 v = pr4[q];
      x0[2+4*q] = v.x; x0[3+4*q] = v.y; x0[4+4*q] = v.z; x0[5+4*q] = v.w;
    }
  } else {
    const float* pr = ptsrc + ((size_t)b3*DF)*NPT + n;
    #pragma unroll
    for(int c=0;c<DF;c++) x0[2+c] = pr[(size_t)c*NPT];
  }

  // ---- layer 0 ----
  float y1[64];
  #pragma unroll
  for(int ch=0; ch<4; ++ch){
    float acc[16];
    #pragma unroll
    for(int oo=0;oo<16;oo++){
      const int o = ch*16+oo;
      float a = 0.f;
      #pragma unroll
      for(int c=0;c<66;c++) a = fmaf(W0[o*66+c], x0[c], a);
      acc[oo] = a;
    }
    if constexpr(DEPTH == 1){
      #pragma unroll
      for(int oo=0;oo<16;oo++){
        float v = wave_sum64(acc[oo]*acc[oo]*wgt);
        if(lane==0) wstat[wv][ch*16+oo] += v;
      }
    } else {
      #pragma unroll
      for(int oo=0;oo<16;oo++){
        const int o = ch*16+oo;
        float xp = acc[oo] * inv1[o];
        acc[oo] = xp;
        sq[c3][r][oo] = xp*xp;
      }
      __syncthreads();
      #pragma unroll
      for(int oo=0;oo<16;oo++){
        float m2 = (sq[0][r][oo] + sq[1][r][oo]) + sq[2][r][oo];
        float mod = sqrtf(m2);
        float cf = (mod >= 1.f) ? 1.f : mod;
        y1[ch*16+oo] = cf * acc[oo];
      }
      __syncthreads();
    }
  }
  if constexpr(DEPTH == 1){
    __syncthreads();
    if(t < 64){
      float sv = 0.f;
      #pragma unroll
      for(int wq=0;wq<6;wq++) sv += wstat[wq][t];
      part[bi*64 + t] = sv;
    }
    return;
  }

  // ---- layer 1 ----
  float y2[64];
  #pragma unroll
  for(int ch=0; ch<4; ++ch){
    float acc[16];
    #pragma unroll
    for(int oo=0;oo<16;oo++){
      const int o = ch*16+oo;
      float a = 0.f;
      #pragma unroll
      for(int c=0;c<64;c++) a = fmaf(W1[o*64+c], y1[c], a);
      acc[oo] = a;
    }
    if constexpr(DEPTH == 2){
      #pragma unroll
      for(int oo=0;oo<16;oo++){
        float v = wave_sum64(acc[oo]*acc[oo]*wgt);
        if(lane==0) wstat[wv][ch*16+oo] += v;
      }
    } else {
      #pragma unroll
      for(int oo=0;oo<16;oo++){
        const int o = ch*16+oo;
        float xp = acc[oo] * inv2[o];
        acc[oo] = xp;
        sq[c3][r][oo] = xp*xp;
      }
      __syncthreads();
      #pragma unroll
      for(int oo=0;oo<16;oo++){
        float m2 = (sq[0][r][oo] + sq[1][r][oo]) + sq[2][r][oo];
        float mod = sqrtf(m2);
        float cf = (mod >= 1.f) ? 1.f : mod;
        y2[ch*16+oo] = cf * acc[oo];
      }
      __syncthreads();
    }
  }
  if constexpr(DEPTH == 2){
    __syncthreads();
    if(t < 64){
      float sv = 0.f;
      #pragma unroll
      for(int wq=0;wq<6;wq++) sv += wstat[wq][t];
      part[bi*64 + t] = sv;
    }
    return;
  }

  // ---- layer 2 + per-group serial argmax + stats3 ----
  #pragma unroll
  for(int ch=0; ch<8; ++ch){
    float a3[16];
    #pragma unroll
    for(int oo=0;oo<16;oo++){
      const int o = ch*16+oo;
      float a = 0.f;
      #pragma unroll
      for(int c=0;c<64;c++) a = fmaf(W2[o*64+c], y2[c], a);
      a3[oo] = a;
      sq[c3][r][oo] = a;          // RAW x3
    }
    __syncthreads();
    if(c3 == 0){
      #pragma unroll
      for(int oo=0;oo<16;oo++){
        float a0 = sq[0][r][oo], a1 = sq[1][r][oo], a2 = sq[2][r][oo];
        float m2 = radd(radd(rmul(a0,a0), rmul(a1,a1)), rmul(a2,a2));
        float v = wave_sum64(m2*wgt);
        if(lane==0) wstat[wv][ch*16+oo] += v;
        if(valid && j==0){
          float bvv = m2; int bjj = 0;
          for(int jj=1; jj<cv; ++jj){
            float c0 = sq[0][r+jj][oo], c1 = sq[1][r+jj][oo], c2 = sq[2][r+jj][oo];
            float mm = radd(radd(rmul(c0,c0), rmul(c1,c1)), rmul(c2,c2));
            if(mm > bvv){ bvv = mm; bjj = jj; }
          }
          const int o = ch*16+oo;
          #pragma unroll
          for(int cc=0;cc<3;cc++){
            out1[(((size_t)(3*b+cc))*128 + o)*NP + s] = sq[cc][r+bjj][oo];
          }
        }
      }
    }
    __syncthreads();
  }
  if(t < 128){
    part[bi*128 + t] = wstat[0][t] + wstat[1][t];
  }
}

// ======================= stats finalize (active tiles only) =======================
__global__ __launch_bounds__(256) void fin_kernel(const float* __restrict__ part,
                                                  const int* __restrict__ ntile_dev, int nch,
                                                  float* __restrict__ inv){
  const int o = blockIdx.x;
  const int t = threadIdx.x;
  const int nblk = *ntile_dev;
  float sum = 0.f;
  for(int i=t; i<nblk; i+=256) sum += part[(size_t)i*nch + o];
  sum = wave_sum64(sum);
  __shared__ float red[4];
  if((t&63)==0) red[t>>6] = sum;
  __syncthreads();
  if(t==0){
    float tot = (red[0]+red[1])+(red[2]+red[3]);
    inv[o] = 1.0f / sqrtf(tot/CNTF + EPSQ);
  }
}

// ======================= fin3 + final qbn+qrelu fused =======================
__global__ __launch_bounds__(256) void fin3_scale(const float* __restrict__ part3,
                                                  const int* __restrict__ ntile_dev,
                                                  float* __restrict__ out){
  const int o = blockIdx.x;
  const int t = threadIdx.x;
  const int nblk = *ntile_dev;
  float sum = 0.f;
  for(int i=t; i<nblk; i+=256) sum += part3[(size_t)i*128 + o];
  sum = wave_sum64(sum);
  __shared__ float red[4];
  __shared__ float sinv;
  if((t&63)==0) red[t>>6] = sum;
  __syncthreads();
  if(t==0){
    float tot = (red[0]+red[1])+(red[2]+red[3]);
    sinv = 1.0f / sqrtf(tot/CNTF + EPSQ);
  }
  __syncthreads();
  const float iv = sinv;
  float* base = out + NB*3*NP;
  const size_t str = (size_t)128*NP;
  for(int idx=t; idx<NB*NP; idx+=256){
    const int b = idx >> 9, s = idx & 511;
    size_t i0 = ((size_t)(b*3)*128 + o)*NP + s;
    float a0 = base[i0] * iv;
    float a1 = base[i0+str] * iv;
    float a2 = base[i0+2*str] * iv;
    float m2 = (a0*a0 + a1*a1) + a2*a2;
    float mod = sqrtf(m2);
    float cf = (mod >= 1.f) ? 1.f : mod;
    base[i0] = cf*a0; base[i0+str] = cf*a1; base[i0+2*str] = cf*a2;
  }
}

// ======================= host =======================
extern "C" void kernel_launch(void* const* d_in, const int* in_sizes, int n_in,
                              void* d_out, int out_size, void* d_ws, size_t ws_size,
                              hipStream_t stream){
  const float* xyz = (const float*)d_in[0];
  const float* pts = (const float*)d_in[1];
  const float* W0  = (const float*)d_in[2];
  const float* W1  = (const float*)d_in[3];
  const float* W2  = (const float*)d_in[4];
  float* out = (float*)d_out;

  char* p = (char*)d_ws;
  auto carve = [&](size_t bytes)->char*{
    char* q = p; p += (bytes + 255) & ~(size_t)255; return q;
  };
  int*   idxb      = (int*)  carve((size_t)NGRP*NS*4);
  int*   cntb      = (int*)  carve((size_t)NGRP*4);
  u32*   witem     = (u32*)  carve((size_t)NTILE_MAX*TSLOT*4);
  int*   ntile_dev = (int*)  carve(256);
  float* part1     = (float*)carve((size_t)NTILE_MAX*64*4);
  float* part2     = (float*)carve((size_t)NTILE_MAX*64*4);
  float* part3     = (float*)carve((size_t)NTILE_MAX*128*4);
  float* inv1      = (float*)carve(64*4);
  float* inv2      = (float*)carve(64*4);
  float* inv3      = (float*)carve(128*4);
  size_t base_need = (size_t)(p - (char*)d_ws);
  float* ptsT      = (float*)p;
  const size_t pt_bytes = (size_t)48*1024*64*4;
  const bool use_pt = (ws_size >= base_need + pt_bytes);

  float* out1 = out + NB*3*NP;

  const int copyblk = (NTILE_MAX*TSLOT + 255)/256;
  if(use_pt) fps_combo<1><<<NB + copyblk, 256, 0, stream>>>(xyz, out, pts, ptsT, witem);
  else       fps_combo<0><<<NB + copyblk, 256, 0, stream>>>(xyz, out, pts, nullptr, witem);

  ball_kernel<<<2048, 256, 0, stream>>>(xyz, out, idxb, cntb);
  pack_kernel<<<1, 1024, 0, stream>>>(cntb, idxb, witem, ntile_dev);

  if(use_pt){
    pass_kernel<1,1><<<NTILE_MAX, 384, 0, stream>>>(xyz, ptsT, W0, W1, W2, out, witem, cntb, ntile_dev, nullptr, nullptr, part1, nullptr);
    fin_kernel<<<64, 256, 0, stream>>>(part1, ntile_dev, 64, inv1);
    pass_kernel<2,1><<<NTILE_MAX, 384, 0, stream>>>(xyz, ptsT, W0, W1, W2, out, witem, cntb, ntile_dev, inv1, nullptr, part2, nullptr);
    fin_kernel<<<64, 256, 0, stream>>>(part2, ntile_dev, 64, inv2);
    pass_kernel<3,1><<<NTILE_MAX, 384, 0, stream>>>(xyz, ptsT, W0, W1, W2, out, witem, cntb, ntile_dev, inv1, inv2, part3, out1);
  } else {
    pass_kernel<1,0><<<NTILE_MAX, 384, 0, stream>>>(xyz, pts, W0, W1, W2, out, witem, cntb, ntile_dev, nullptr, nullptr, part1, nullptr);
    fin_kernel<<<64, 256, 0, stream>>>(part1, ntile_dev, 64, inv1);
    pass_kernel<2,0><<<NTILE_MAX, 384, 0, stream>>>(xyz, pts, W0, W1, W2, out, witem, cntb, ntile_dev, inv1, nullptr, part2, nullptr);
    fin_kernel<<<64, 256, 0, stream>>>(part2, ntile_dev, 64, inv2);
    pass_kernel<3,0><<<NTILE_MAX, 384, 0, stream>>>(xyz, pts, W0, W1, W2, out, witem, cntb, ntile_dev, inv1, inv2, part3, out1);
  }
  fin3_scale<<<128, 256, 0, stream>>>(part3, ntile_dev, out);
}

// Round 7
// 775.549 us; speedup vs baseline: 1.6779x; 1.6779x over previous
//
#include <hip/hip_runtime.h>

typedef unsigned int u32;

#define NB 16
#define NPT 1024
#define NP 512
#define NS 32
#define DF 64
#define RAD2 0.04f
#define EPSQ 1e-5f
#define CNTF 786432.0f   // 48*512*32
#define NGRP 8192        // NB*NP
#define TCAP 96
#define TSLOT 128
#define NTILE_MAX 2731   // ceil(NGRP*NS / TCAP)

// --- np-matching (contraction-proof) arithmetic -------------------------
__device__ __forceinline__ float rmul(float a, float b){ return __fmul_rn(a,b); }
__device__ __forceinline__ float radd(float a, float b){ return __fadd_rn(a,b); }
__device__ __forceinline__ float sq3(float a, float b, float c){
  return radd(radd(rmul(a,a), rmul(b,b)), rmul(c,c));
}

__device__ __forceinline__ float wave_sum64(float v){
  #pragma unroll
  for(int m=1;m<64;m<<=1) v += __shfl_xor(v, m, 64);
  return v;
}

// DPP argmax combine carrying (dist m, index mi): take candidate if strictly
// greater, or equal with smaller index. All-VALU.
#define DPPCOMB(CTRL) do{ \
  float _ov = __int_as_float(__builtin_amdgcn_mov_dpp(__float_as_int(m), (CTRL), 0xF, 0xF, true)); \
  int   _oi = __builtin_amdgcn_mov_dpp(mi, (CTRL), 0xF, 0xF, true); \
  bool _tk = (_ov > m) || (_ov == m && _oi < mi); \
  m = _tk ? _ov : m; mi = _tk ? _oi : mi; \
}while(0)

// Full-wave argmax over dist[16]/lane (global index n = lane*16 + j).
// Adjacent pairing at every tree level => tie -> lower index exactly.
__device__ __forceinline__ int wave_argmax1024(const float* dist, int lane){
  float v8[8]; int j8[8];
  #pragma unroll
  for(int q=0;q<8;q++){
    bool tk = dist[2*q+1] > dist[2*q];
    v8[q] = tk ? dist[2*q+1] : dist[2*q];
    j8[q] = tk ? 2*q+1 : 2*q;
  }
  float v4[4]; int j4[4];
  #pragma unroll
  for(int q=0;q<4;q++){
    bool tk = v8[2*q+1] > v8[2*q];
    v4[q] = tk ? v8[2*q+1] : v8[2*q];
    j4[q] = tk ? j8[2*q+1] : j8[2*q];
  }
  float v2[2]; int j2[2];
  #pragma unroll
  for(int q=0;q<2;q++){
    bool tk = v4[2*q+1] > v4[2*q];
    v2[q] = tk ? v4[2*q+1] : v4[2*q];
    j2[q] = tk ? j4[2*q+1] : j4[2*q];
  }
  bool tk = v2[1] > v2[0];
  float m  = tk ? v2[1] : v2[0];
  int   mi = lane*16 + (tk ? j2[1] : j2[0]);
  DPPCOMB(0xB1);   // quad_perm xor1
  DPPCOMB(0x4E);   // quad_perm xor2
  DPPCOMB(0x124);  // row_ror:4
  DPPCOMB(0x128);  // row_ror:8   -> row-16 reduced everywhere
  DPPCOMB(0x142);  // row_bcast15
  DPPCOMB(0x143);  // row_bcast31 -> lane 63 holds full 64-lane argmax
  return __builtin_amdgcn_readlane(mi, 63);
}

// ======================= FPS (single wave, store-free loop) + prep =========
// The serial loop has NO stores: selected coords are kept in per-chunk
// registers (lane it&63 owns iteration it of chunk it>>6) and flushed with
// 24 coalesced stores at the end. Loads xb[far] are wave-uniform (L1/sK$).
template<int PT>
__global__ __launch_bounds__(256) void fps_combo(const float* __restrict__ xyz,
                                                 float* __restrict__ out0,
                                                 const float* __restrict__ pts,
                                                 float* __restrict__ ptsT,
                                                 u32* __restrict__ witem){
  const int bid = blockIdx.x;
  const int t = threadIdx.x;
  if(bid >= NB){
    const int gid = (bid - NB)*256 + t;
    if(gid < NTILE_MAX*TSLOT) witem[gid] = 0xFFFFFFFFu;
    if constexpr(PT){
      const int w = gid >> 6, ln = gid & 63;
      if(w < 48*16){
        const int b3 = w >> 4, n0 = (w & 15) << 6;
        const float* src = pts + (((size_t)b3*64 + ln) << 10);
        float* dst = ptsT + (((size_t)b3*1024 + n0) << 6) + ln;
        #pragma unroll 4
        for(int i=0;i<64;i++) dst[(size_t)i << 6] = src[n0 + i];
      }
    }
    return;
  }
  if(t >= 64) return;
  const int lane = t;
  const int b = bid;
  const float* xb = xyz + b*3*NPT;
  const float* yb = xb + NPT;
  const float* zb = xb + 2*NPT;
  float px[16], py[16], pz[16], dist[16];
  #pragma unroll
  for(int j=0;j<16;j++){
    const int n = lane*16 + j;
    px[j] = xb[n]; py[j] = yb[n]; pz[j] = zb[n];
  }
  // centroid (once)
  float sx=0.f, sy=0.f, sz=0.f;
  #pragma unroll
  for(int j=0;j<16;j++){ sx+=px[j]; sy+=py[j]; sz+=pz[j]; }
  sx = wave_sum64(sx); sy = wave_sum64(sy); sz = wave_sum64(sz);
  const float cx = sx/1024.f, cy = sy/1024.f, cz = sz/1024.f;
  #pragma unroll
  for(int j=0;j<16;j++){
    float dx = px[j]-cx, dy = py[j]-cy, dz = pz[j]-cz;
    dist[j] = fminf(1e10f, sq3(dx,dy,dz));
  }
  int far = wave_argmax1024(dist, lane);

  float qsx[8], qsy[8], qsz[8];
  #pragma unroll
  for(int u=0; u<8; ++u){
    for(int v=0; v<64; ++v){
      // coords of current selection (wave-uniform address -> cached)
      const float qx = xb[far], qy = yb[far], qz = zb[far];
      // save into this chunk's register at lane v (static chunk index u)
      const bool mine = (lane == v);
      qsx[u] = mine ? qx : qsx[u];
      qsy[u] = mine ? qy : qsy[u];
      qsz[u] = mine ? qz : qsz[u];
      // distance update (bit-identical rounding/order to reference)
      #pragma unroll
      for(int j=0;j<16;j++){
        float dx = px[j]-qx, dy = py[j]-qy, dz = pz[j]-qz;
        float nd = sq3(dx,dy,dz);
        dist[j] = fminf(dist[j], nd);
      }
      far = wave_argmax1024(dist, lane);
    }
  }
  // flush: 24 coalesced stores
  #pragma unroll
  for(int u=0;u<8;u++){
    out0[(b*3+0)*NP + u*64 + lane] = qsx[u];
    out0[(b*3+1)*NP + u*64 + lane] = qsy[u];
    out0[(b*3+2)*NP + u*64 + lane] = qsz[u];
  }
}

// ======================= Ball query (+cnt) =======================
__global__ __launch_bounds__(256) void ball_kernel(const float* __restrict__ xyz,
                                                   const float* __restrict__ out0,
                                                   int* __restrict__ idxb,
                                                   int* __restrict__ cntb){
  const int gw = (blockIdx.x * 256 + threadIdx.x) >> 6;
  const int lane = threadIdx.x & 63;
  const int b = gw >> 9;
  const int s = gw & 511;
  const float s0 = out0[(b*3+0)*NP + s];
  const float s1 = out0[(b*3+1)*NP + s];
  const float s2 = out0[(b*3+2)*NP + s];
  const float ss = sq3(s0,s1,s2);
  const float* xb = xyz + b*3*NPT;
  int base = 0;
  int* row = idxb + (b*NP + s)*NS;
  for(int chk=0; chk<16 && base<NS; ++chk){
    const int n = chk*64 + lane;
    float d0 = xb[n], d1 = xb[NPT+n], d2 = xb[2*NPT+n];
    float dd = sq3(d0,d1,d2);
    float p  = radd(radd(rmul(s0,d0), rmul(s1,d1)), rmul(s2,d2));
    float sqr = radd(radd(rmul(-2.0f,p), ss), dd);
    bool inc = !(sqr > RAD2);
    unsigned long long mask = __ballot(inc);
    if(inc){
      int slot = base + __popcll(mask & ((1ull<<lane)-1ull));
      if(slot < NS) row[slot] = n;
    }
    base += __popcll(mask);
  }
  if(lane==0) cntb[gw] = (base < NS) ? base : NS;
}

// ======================= pack: 1024 threads, 8 groups each =======================
__global__ __launch_bounds__(1024) void pack_kernel(const int* __restrict__ cntb,
                                                    const int* __restrict__ idxb,
                                                    u32* __restrict__ witem,
                                                    int* __restrict__ ntile_dev){
  const int t = threadIdx.x;
  const int lane = t & 63;
  const int wv = t >> 6;
  int c[8]; int s0 = 0;
  #pragma unroll
  for(int i=0;i<8;i++){ c[i] = cntb[t*8+i]; s0 += c[i]; }
  int pre = s0;
  #pragma unroll
  for(int d=1; d<64; d<<=1){
    int v = __shfl_up(pre, d, 64);
    if(lane >= d) pre += v;
  }
  __shared__ int wsum[16];
  if(lane==63) wsum[wv] = pre;
  __syncthreads();
  int wo = 0;
  #pragma unroll
  for(int w=0;w<16;w++) if(w < wv) wo += wsum[w];
  int m = wo + pre - s0;
  if(t==1023) *ntile_dev = (wo + pre + TCAP - 1) / TCAP;
  #pragma unroll
  for(int i=0;i<8;i++){
    const int g = t*8+i; const int cc = c[i];
    const int tile = m / TCAP; const int slot = m - TCAP*tile;
    const int* row = idxb + g*NS;
    for(int j=0;j<cc;j++){
      witem[tile*TSLOT + slot + j] = (u32)((g<<15) | (j<<10) | row[j]);
    }
    m += cc;
  }
}

// ======================= Fused MLP chain over packed tiles =======================
template<int DEPTH, int PT>
__global__ __launch_bounds__(384) void pass_kernel(
  const float* __restrict__ xyz, const float* __restrict__ ptsrc,
  const float* __restrict__ W0, const float* __restrict__ W1, const float* __restrict__ W2,
  const float* __restrict__ out0, const u32* __restrict__ witem,
  const int* __restrict__ cntb, const int* __restrict__ ntile_dev,
  const float* __restrict__ inv1, const float* __restrict__ inv2,
  float* __restrict__ part, float* __restrict__ out1)
{
  const int t = threadIdx.x;
  const int c3 = t >> 7;
  const int r  = t & 127;
  const int lane = t & 63;
  const int wv = t >> 6;
  const int bi = blockIdx.x;

  if(bi >= *ntile_dev) return;   // fin reduces only active tiles

  __shared__ float sq[3][128][17];
  __shared__ float wstat[6][128];
  for(int i=t; i<6*128; i+=384) (&wstat[0][0])[i] = 0.f;
  __syncthreads();

  const u32 w = witem[bi*TSLOT + r];
  const bool valid = (w != 0xFFFFFFFFu);
  const int bs = valid ? (int)(w >> 15) : 0;
  const int j  = valid ? (int)((w >> 10) & 31) : 1;
  const int n  = valid ? (int)(w & 1023) : 0;
  const int b = bs >> 9;
  const int s = bs & 511;
  const int b3 = b*3 + c3;
  const int cv = cntb[bs];
  const float wgt = valid ? ((j==0) ? (float)(33 - cv) : 1.0f) : 0.0f;

  const float gx = xyz[b3*NPT + n];
  const float cx = out0[b3*NP + s];
  float x0[66];
  x0[0] = gx - cx;
  x0[1] = gx;
  if constexpr(PT){
    const float4* pr4 = reinterpret_cast<const float4*>(ptsrc + (((size_t)b3<<10) + (size_t)n)*DF);
    #pragma unroll
    for(int q=0;q<16;q++){
      float4 v = pr4[q];
      x0[2+4*q] = v.x; x0[3+4*q] = v.y; x0[4+4*q] = v.z; x0[5+4*q] = v.w;
    }
  } else {
    const float* pr = ptsrc + ((size_t)b3*DF)*NPT + n;
    #pragma unroll
    for(int c=0;c<DF;c++) x0[2+c] = pr[(size_t)c*NPT];
  }

  // ---- layer 0 ----
  float y1[64];
  #pragma unroll
  for(int ch=0; ch<4; ++ch){
    float acc[16];
    #pragma unroll
    for(int oo=0;oo<16;oo++){
      const int o = ch*16+oo;
      float a = 0.f;
      #pragma unroll
      for(int c=0;c<66;c++) a = fmaf(W0[o*66+c], x0[c], a);
      acc[oo] = a;
    }
    if constexpr(DEPTH == 1){
      #pragma unroll
      for(int oo=0;oo<16;oo++){
        float v = wave_sum64(acc[oo]*acc[oo]*wgt);
        if(lane==0) wstat[wv][ch*16+oo] += v;
      }
    } else {
      #pragma unroll
      for(int oo=0;oo<16;oo++){
        const int o = ch*16+oo;
        float xp = acc[oo] * inv1[o];
        acc[oo] = xp;
        sq[c3][r][oo] = xp*xp;
      }
      __syncthreads();
      #pragma unroll
      for(int oo=0;oo<16;oo++){
        float m2 = (sq[0][r][oo] + sq[1][r][oo]) + sq[2][r][oo];
        float mod = sqrtf(m2);
        float cf = (mod >= 1.f) ? 1.f : mod;
        y1[ch*16+oo] = cf * acc[oo];
      }
      __syncthreads();
    }
  }
  if constexpr(DEPTH == 1){
    __syncthreads();
    if(t < 64){
      float sv = 0.f;
      #pragma unroll
      for(int wq=0;wq<6;wq++) sv += wstat[wq][t];
      part[bi*64 + t] = sv;
    }
    return;
  }

  // ---- layer 1 ----
  float y2[64];
  #pragma unroll
  for(int ch=0; ch<4; ++ch){
    float acc[16];
    #pragma unroll
    for(int oo=0;oo<16;oo++){
      const int o = ch*16+oo;
      float a = 0.f;
      #pragma unroll
      for(int c=0;c<64;c++) a = fmaf(W1[o*64+c], y1[c], a);
      acc[oo] = a;
    }
    if constexpr(DEPTH == 2){
      #pragma unroll
      for(int oo=0;oo<16;oo++){
        float v = wave_sum64(acc[oo]*acc[oo]*wgt);
        if(lane==0) wstat[wv][ch*16+oo] += v;
      }
    } else {
      #pragma unroll
      for(int oo=0;oo<16;oo++){
        const int o = ch*16+oo;
        float xp = acc[oo] * inv2[o];
        acc[oo] = xp;
        sq[c3][r][oo] = xp*xp;
      }
      __syncthreads();
      #pragma unroll
      for(int oo=0;oo<16;oo++){
        float m2 = (sq[0][r][oo] + sq[1][r][oo]) + sq[2][r][oo];
        float mod = sqrtf(m2);
        float cf = (mod >= 1.f) ? 1.f : mod;
        y2[ch*16+oo] = cf * acc[oo];
      }
      __syncthreads();
    }
  }
  if constexpr(DEPTH == 2){
    __syncthreads();
    if(t < 64){
      float sv = 0.f;
      #pragma unroll
      for(int wq=0;wq<6;wq++) sv += wstat[wq][t];
      part[bi*64 + t] = sv;
    }
    return;
  }

  // ---- layer 2 + per-group serial argmax + stats3 ----
  #pragma unroll
  for(int ch=0; ch<8; ++ch){
    float a3[16];
    #pragma unroll
    for(int oo=0;oo<16;oo++){
      const int o = ch*16+oo;
      float a = 0.f;
      #pragma unroll
      for(int c=0;c<64;c++) a = fmaf(W2[o*64+c], y2[c], a);
      a3[oo] = a;
      sq[c3][r][oo] = a;          // RAW x3
    }
    __syncthreads();
    if(c3 == 0){
      #pragma unroll
      for(int oo=0;oo<16;oo++){
        float a0 = sq[0][r][oo], a1 = sq[1][r][oo], a2 = sq[2][r][oo];
        float m2 = radd(radd(rmul(a0,a0), rmul(a1,a1)), rmul(a2,a2));
        float v = wave_sum64(m2*wgt);
        if(lane==0) wstat[wv][ch*16+oo] += v;
        if(valid && j==0){
          float bvv = m2; int bjj = 0;
          for(int jj=1; jj<cv; ++jj){
            float c0 = sq[0][r+jj][oo], c1 = sq[1][r+jj][oo], c2 = sq[2][r+jj][oo];
            float mm = radd(radd(rmul(c0,c0), rmul(c1,c1)), rmul(c2,c2));
            if(mm > bvv){ bvv = mm; bjj = jj; }
          }
          const int o = ch*16+oo;
          #pragma unroll
          for(int cc=0;cc<3;cc++){
            out1[(((size_t)(3*b+cc))*128 + o)*NP + s] = sq[cc][r+bjj][oo];
          }
        }
      }
    }
    __syncthreads();
  }
  if(t < 128){
    part[bi*128 + t] = wstat[0][t] + wstat[1][t];
  }
}

// ======================= stats finalize (active tiles only) =======================
__global__ __launch_bounds__(256) void fin_kernel(const float* __restrict__ part,
                                                  const int* __restrict__ ntile_dev, int nch,
                                                  float* __restrict__ inv){
  const int o = blockIdx.x;
  const int t = threadIdx.x;
  const int nblk = *ntile_dev;
  float sum = 0.f;
  for(int i=t; i<nblk; i+=256) sum += part[(size_t)i*nch + o];
  sum = wave_sum64(sum);
  __shared__ float red[4];
  if((t&63)==0) red[t>>6] = sum;
  __syncthreads();
  if(t==0){
    float tot = (red[0]+red[1])+(red[2]+red[3]);
    inv[o] = 1.0f / sqrtf(tot/CNTF + EPSQ);
  }
}

// ======================= fin3 + final qbn+qrelu fused =======================
__global__ __launch_bounds__(256) void fin3_scale(const float* __restrict__ part3,
                                                  const int* __restrict__ ntile_dev,
                                                  float* __restrict__ out){
  const int o = blockIdx.x;
  const int t = threadIdx.x;
  const int nblk = *ntile_dev;
  float sum = 0.f;
  for(int i=t; i<nblk; i+=256) sum += part3[(size_t)i*128 + o];
  sum = wave_sum64(sum);
  __shared__ float red[4];
  __shared__ float sinv;
  if((t&63)==0) red[t>>6] = sum;
  __syncthreads();
  if(t==0){
    float tot = (red[0]+red[1])+(red[2]+red[3]);
    sinv = 1.0f / sqrtf(tot/CNTF + EPSQ);
  }
  __syncthreads();
  const float iv = sinv;
  float* base = out + NB*3*NP;
  const size_t str = (size_t)128*NP;
  for(int idx=t; idx<NB*NP; idx+=256){
    const int b = idx >> 9, s = idx & 511;
    size_t i0 = ((size_t)(b*3)*128 + o)*NP + s;
    float a0 = base[i0] * iv;
    float a1 = base[i0+str] * iv;
    float a2 = base[i0+2*str] * iv;
    float m2 = (a0*a0 + a1*a1) + a2*a2;
    float mod = sqrtf(m2);
    float cf = (mod >= 1.f) ? 1.f : mod;
    base[i0] = cf*a0; base[i0+str] = cf*a1; base[i0+2*str] = cf*a2;
  }
}

// ======================= host =======================
extern "C" void kernel_launch(void* const* d_in, const int* in_sizes, int n_in,
                              void* d_out, int out_size, void* d_ws, size_t ws_size,
                              hipStream_t stream){
  const float* xyz = (const float*)d_in[0];
  const float* pts = (const float*)d_in[1];
  const float* W0  = (const float*)d_in[2];
  const float* W1  = (const float*)d_in[3];
  const float* W2  = (const float*)d_in[4];
  float* out = (float*)d_out;

  char* p = (char*)d_ws;
  auto carve = [&](size_t bytes)->char*{
    char* q = p; p += (bytes + 255) & ~(size_t)255; return q;
  };
  int*   idxb      = (int*)  carve((size_t)NGRP*NS*4);
  int*   cntb      = (int*)  carve((size_t)NGRP*4);
  u32*   witem     = (u32*)  carve((size_t)NTILE_MAX*TSLOT*4);
  int*   ntile_dev = (int*)  carve(256);
  float* part1     = (float*)carve((size_t)NTILE_MAX*64*4);
  float* part2     = (float*)carve((size_t)NTILE_MAX*64*4);
  float* part3     = (float*)carve((size_t)NTILE_MAX*128*4);
  float* inv1      = (float*)carve(64*4);
  float* inv2      = (float*)carve(64*4);
  float* inv3      = (float*)carve(128*4);
  size_t base_need = (size_t)(p - (char*)d_ws);
  float* ptsT      = (float*)p;
  const size_t pt_bytes = (size_t)48*1024*64*4;
  const bool use_pt = (ws_size >= base_need + pt_bytes);

  float* out1 = out + NB*3*NP;

  const int copyblk = (NTILE_MAX*TSLOT + 255)/256;
  if(use_pt) fps_combo<1><<<NB + copyblk, 256, 0, stream>>>(xyz, out, pts, ptsT, witem);
  else       fps_combo<0><<<NB + copyblk, 256, 0, stream>>>(xyz, out, pts, nullptr, witem);

  ball_kernel<<<2048, 256, 0, stream>>>(xyz, out, idxb, cntb);
  pack_kernel<<<1, 1024, 0, stream>>>(cntb, idxb, witem, ntile_dev);

  if(use_pt){
    pass_kernel<1,1><<<NTILE_MAX, 384, 0, stream>>>(xyz, ptsT, W0, W1, W2, out, witem, cntb, ntile_dev, nullptr, nullptr, part1, nullptr);
    fin_kernel<<<64, 256, 0, stream>>>(part1, ntile_dev, 64, inv1);
    pass_kernel<2,1><<<NTILE_MAX, 384, 0, stream>>>(xyz, ptsT, W0, W1, W2, out, witem, cntb, ntile_dev, inv1, nullptr, part2, nullptr);
    fin_kernel<<<64, 256, 0, stream>>>(part2, ntile_dev, 64, inv2);
    pass_kernel<3,1><<<NTILE_MAX, 384, 0, stream>>>(xyz, ptsT, W0, W1, W2, out, witem, cntb, ntile_dev, inv1, inv2, part3, out1);
  } else {
    pass_kernel<1,0><<<NTILE_MAX, 384, 0, stream>>>(xyz, pts, W0, W1, W2, out, witem, cntb, ntile_dev, nullptr, nullptr, part1, nullptr);
    fin_kernel<<<64, 256, 0, stream>>>(part1, ntile_dev, 64, inv1);
    pass_kernel<2,0><<<NTILE_MAX, 384, 0, stream>>>(xyz, pts, W0, W1, W2, out, witem, cntb, ntile_dev, inv1, nullptr, part2, nullptr);
    fin_kernel<<<64, 256, 0, stream>>>(part2, ntile_dev, 64, inv2);
    pass_kernel<3,0><<<NTILE_MAX, 384, 0, stream>>>(xyz, pts, W0, W1, W2, out, witem, cntb, ntile_dev, inv1, inv2, part3, out1);
  }
  fin3_scale<<<128, 256, 0, stream>>>(part3, ntile_dev, out);
}